// Round 1
// baseline (3067.201 us; speedup 1.0000x reference)
//
#include <hip/hip_runtime.h>
#include <hip/hip_bf16.h>

#define NUM_NODES 100000
#define NUM_EDGES 100000
#define NNZ       1600000
#define D         64

// ---------------------------------------------------------------------------
// Kernel 1: Xp = X @ W^T + b   (W stored [out, in] = [64, 64])
// Block: 256 threads, 32 rows/block. Each thread owns one output column c for
// 8 rows. W staged in LDS with +1 padding (bank-conflict-free: (65c+k)%32
// covers all banks at 2-way aliasing, which is free on gfx950).
// ---------------------------------------------------------------------------
#define GEMM_ROWS 32
__global__ __launch_bounds__(256) void gemm_xw(
    const float* __restrict__ X, const float* __restrict__ W,
    const float* __restrict__ b, float* __restrict__ Xp) {
  __shared__ float Wl[D][D + 1];
  __shared__ float Xl[GEMM_ROWS][D];
  const int t = threadIdx.x;

  // stage W (4096 floats)
  for (int j = t; j < D * D; j += 256) Wl[j >> 6][j & 63] = W[j];
  // stage 32 rows of X (2048 floats) as float4
  const int row0 = blockIdx.x * GEMM_ROWS;
  const float4* X4 = (const float4*)(X + (size_t)row0 * D);
  float4* Xl4 = (float4*)&Xl[0][0];
  for (int j = t; j < GEMM_ROWS * (D / 4); j += 256) Xl4[j] = X4[j];
  __syncthreads();

  const int c = t & 63;      // output column
  const int rq = t >> 6;     // row quadrant 0..3
  float acc[8];
#pragma unroll
  for (int i = 0; i < 8; ++i) acc[i] = 0.f;
#pragma unroll
  for (int k = 0; k < D; ++k) {
    const float w = Wl[c][k];
#pragma unroll
    for (int i = 0; i < 8; ++i) acc[i] = fmaf(Xl[rq + i * 4][k], w, acc[i]);
  }
  const float bias = b[c];
#pragma unroll
  for (int i = 0; i < 8; ++i) {
    const int r = row0 + rq + i * 4;
    Xp[(size_t)r * D + c] = acc[i] + bias;
  }
}

// ---------------------------------------------------------------------------
// Kernel 2: degree counts.  D_v[v] += 1, cnt_e[e] += 1 per incidence.
// ---------------------------------------------------------------------------
__global__ __launch_bounds__(256) void degrees_k(
    const int* __restrict__ V, const int* __restrict__ E,
    float* __restrict__ D_v, float* __restrict__ cnt_e) {
  const int i = blockIdx.x * blockDim.x + threadIdx.x;
  if (i < NNZ) {
    atomicAdd(&D_v[V[i]], 1.0f);
    atomicAdd(&cnt_e[E[i]], 1.0f);
  }
}

// ---------------------------------------------------------------------------
// Kernel 3: De_sum[e] += D_v[v] per incidence (needs D_v complete).
// ---------------------------------------------------------------------------
__global__ __launch_bounds__(256) void de_sum_k(
    const int* __restrict__ V, const int* __restrict__ E,
    const float* __restrict__ D_v, float* __restrict__ De_sum) {
  const int i = blockIdx.x * blockDim.x + threadIdx.x;
  if (i < NNZ) {
    atomicAdd(&De_sum[E[i]], D_v[V[i]]);
  }
}

// ---------------------------------------------------------------------------
// Kernel 4: per-edge combined scale = De_inv(e) / max(cnt_e, 1)
//   De = De_sum/(cnt+1);  De_inv = De>0 ? rsqrt(max(De,1e-30)) : 1
// ---------------------------------------------------------------------------
__global__ __launch_bounds__(256) void edge_scale_k(
    const float* __restrict__ De_sum, const float* __restrict__ cnt_e,
    float* __restrict__ scale_e) {
  const int e = blockIdx.x * blockDim.x + threadIdx.x;
  if (e < NUM_EDGES) {
    const float cnt = cnt_e[e];
    const float De = De_sum[e] / (cnt + 1.0f);
    const float inv = (De > 0.f) ? rsqrtf(fmaxf(De, 1e-30f)) : 1.0f;
    scale_e[e] = inv / fmaxf(cnt, 1.0f);
  }
}

// ---------------------------------------------------------------------------
// Kernel 5: Y[e,:] += Xp[v,:] per incidence.  16 lanes per incidence, one
// float4 gather per lane (256 B contiguous per row), 4 scalar atomics out.
// ---------------------------------------------------------------------------
__global__ __launch_bounds__(256) void scatter_y_k(
    const int* __restrict__ V, const int* __restrict__ E,
    const float* __restrict__ Xp, float* __restrict__ Y) {
  const int g = blockIdx.x * blockDim.x + threadIdx.x;
  const int i = g >> 4;          // incidence index
  const int q = g & 15;          // float4 slot within the 64-wide row
  if (i < NNZ) {
    const int v = V[i];
    const int e = E[i];
    const float4 x = ((const float4*)Xp)[v * (D / 4) + q];
    float* yp = Y + (size_t)e * D + q * 4;
    atomicAdd(yp + 0, x.x);
    atomicAdd(yp + 1, x.y);
    atomicAdd(yp + 2, x.z);
    atomicAdd(yp + 3, x.w);
  }
}

// ---------------------------------------------------------------------------
// Kernel 6: Out[v,:] += scale_e[e] * Y[e,:] per incidence.
// ---------------------------------------------------------------------------
__global__ __launch_bounds__(256) void scatter_x_k(
    const int* __restrict__ V, const int* __restrict__ E,
    const float* __restrict__ Y, const float* __restrict__ scale_e,
    float* __restrict__ Out) {
  const int g = blockIdx.x * blockDim.x + threadIdx.x;
  const int i = g >> 4;
  const int q = g & 15;
  if (i < NNZ) {
    const int v = V[i];
    const int e = E[i];
    const float s = scale_e[e];
    const float4 y = ((const float4*)Y)[e * (D / 4) + q];
    float* op = Out + (size_t)v * D + q * 4;
    atomicAdd(op + 0, y.x * s);
    atomicAdd(op + 1, y.y * s);
    atomicAdd(op + 2, y.z * s);
    atomicAdd(op + 3, y.w * s);
  }
}

// ---------------------------------------------------------------------------
// Kernel 7: Out[v,:] *= Dv_inv(v)
// ---------------------------------------------------------------------------
__global__ __launch_bounds__(256) void finalize_k(
    float* __restrict__ Out, const float* __restrict__ D_v) {
  const int g = blockIdx.x * blockDim.x + threadIdx.x;  // one float4 each
  if (g < NUM_NODES * (D / 4)) {
    const int v = g >> 4;
    const float d = D_v[v];
    const float s = (d > 0.f) ? rsqrtf(d) : 0.f;
    float4* o = (float4*)Out;
    float4 x = o[g];
    x.x *= s; x.y *= s; x.z *= s; x.w *= s;
    o[g] = x;
  }
}

extern "C" void kernel_launch(void* const* d_in, const int* in_sizes, int n_in,
                              void* d_out, int out_size, void* d_ws, size_t ws_size,
                              hipStream_t stream) {
  const float* X = (const float*)d_in[0];
  const int*   V = (const int*)d_in[1];
  const int*   E = (const int*)d_in[2];
  // d_in[3] = S_features (unused by forward)
  const float* W = (const float*)d_in[4];
  const float* b = (const float*)d_in[5];
  float* Out = (float*)d_out;

  // workspace layout (bytes)
  char* ws = (char*)d_ws;
  float* Xp      = (float*)(ws);                                   // 25.6 MB
  float* Y       = (float*)(ws + (size_t)NUM_NODES * D * 4);       // 25.6 MB
  float* cnt_e   = (float*)(ws + (size_t)(NUM_NODES + NUM_EDGES) * D * 4);       // 400 KB
  float* D_v     = cnt_e + NUM_EDGES;                              // 400 KB
  float* De_sum  = D_v + NUM_NODES;                                // 400 KB
  float* scale_e = De_sum + NUM_EDGES;                             // 400 KB

  // zero the accumulators (ws/out are poisoned 0xAA before every call)
  hipMemsetAsync(Y, 0, (size_t)NUM_EDGES * D * 4, stream);
  hipMemsetAsync(cnt_e, 0, (size_t)(NUM_EDGES + NUM_NODES + NUM_EDGES) * 4, stream);
  hipMemsetAsync(Out, 0, (size_t)NUM_NODES * D * 4, stream);

  // 1. projection
  gemm_xw<<<NUM_NODES / GEMM_ROWS, 256, 0, stream>>>(X, W, b, Xp);
  // 2. degrees
  degrees_k<<<(NNZ + 255) / 256, 256, 0, stream>>>(V, E, D_v, cnt_e);
  // 3. De_sum
  de_sum_k<<<(NNZ + 255) / 256, 256, 0, stream>>>(V, E, D_v, De_sum);
  // 4. per-edge scale
  edge_scale_k<<<(NUM_EDGES + 255) / 256, 256, 0, stream>>>(De_sum, cnt_e, scale_e);
  // 5. Y accumulation (1.6M x 64 atomics)
  {
    const long total = (long)NNZ * 16;
    scatter_y_k<<<(int)((total + 255) / 256), 256, 0, stream>>>(V, E, Xp, Y);
  }
  // 6. node accumulation with fused edge scaling
  {
    const long total = (long)NNZ * 16;
    scatter_x_k<<<(int)((total + 255) / 256), 256, 0, stream>>>(V, E, Y, scale_e, Out);
  }
  // 7. final node scaling
  {
    const int total = NUM_NODES * (D / 4);
    finalize_k<<<(total + 255) / 256, 256, 0, stream>>>(Out, D_v);
  }
}

// Round 2
// 654.188 us; speedup vs baseline: 4.6886x; 4.6886x over previous
//
#include <hip/hip_runtime.h>
#include <hip/hip_bf16.h>

#define NUM_NODES 100000
#define NUM_EDGES 100000
#define NNZ       1600000
#define D         64

// concatenated count/offset layout: [0, NUM_EDGES) = edges, [NUM_EDGES, N2) = nodes
#define N2 (NUM_EDGES + NUM_NODES)          // 200000
#define SCAN_B 256
#define NB ((N2 + SCAN_B - 1) / SCAN_B)     // 782

// ---------------------------------------------------------------------------
// Kernel 1: Xp = X @ W^T + b   (W stored [out, in] = [64, 64])
// ---------------------------------------------------------------------------
#define GEMM_ROWS 32
__global__ __launch_bounds__(256) void gemm_xw(
    const float* __restrict__ X, const float* __restrict__ W,
    const float* __restrict__ b, float* __restrict__ Xp) {
  __shared__ float Wl[D][D + 1];
  __shared__ float Xl[GEMM_ROWS][D];
  const int t = threadIdx.x;

  for (int j = t; j < D * D; j += 256) Wl[j >> 6][j & 63] = W[j];
  const int row0 = blockIdx.x * GEMM_ROWS;
  const float4* X4 = (const float4*)(X + (size_t)row0 * D);
  float4* Xl4 = (float4*)&Xl[0][0];
  for (int j = t; j < GEMM_ROWS * (D / 4); j += 256) Xl4[j] = X4[j];
  __syncthreads();

  const int c = t & 63;
  const int rq = t >> 6;
  float acc[8];
#pragma unroll
  for (int i = 0; i < 8; ++i) acc[i] = 0.f;
#pragma unroll
  for (int k = 0; k < D; ++k) {
    const float w = Wl[c][k];
#pragma unroll
    for (int i = 0; i < 8; ++i) acc[i] = fmaf(Xl[rq + i * 4][k], w, acc[i]);
  }
  const float bias = b[c];
#pragma unroll
  for (int i = 0; i < 8; ++i) {
    const int r = row0 + rq + i * 4;
    Xp[(size_t)r * D + c] = acc[i] + bias;
  }
}

// ---------------------------------------------------------------------------
// Kernel 2: histogram — cnt[e]++ and cnt[NUM_EDGES+v]++ per incidence
// ---------------------------------------------------------------------------
__global__ __launch_bounds__(256) void hist_k(
    const int* __restrict__ V, const int* __restrict__ E, int* __restrict__ cnt) {
  const int i = blockIdx.x * blockDim.x + threadIdx.x;
  if (i < NNZ) {
    atomicAdd(&cnt[E[i]], 1);
    atomicAdd(&cnt[NUM_EDGES + V[i]], 1);
  }
}

// ---------------------------------------------------------------------------
// Scan (exclusive prefix sum over cnt[N2] -> off[N2+1]), 3 kernels
// ---------------------------------------------------------------------------
__global__ __launch_bounds__(SCAN_B) void scan_reduce_k(
    const int* __restrict__ cnt, int* __restrict__ bsum) {
  __shared__ int s[SCAN_B];
  const int t = threadIdx.x, b = blockIdx.x, i = b * SCAN_B + t;
  s[t] = (i < N2) ? cnt[i] : 0;
  __syncthreads();
  for (int st = SCAN_B / 2; st > 0; st >>= 1) {
    if (t < st) s[t] += s[t + st];
    __syncthreads();
  }
  if (t == 0) bsum[b] = s[0];
}

__global__ __launch_bounds__(1024) void scan_mid_k(
    const int* __restrict__ bsum, int* __restrict__ boff) {
  __shared__ int s[1024];
  const int t = threadIdx.x;
  s[t] = (t < NB) ? bsum[t] : 0;
  __syncthreads();
  for (int st = 1; st < 1024; st <<= 1) {
    const int v = s[t];
    const int add = (t >= st) ? s[t - st] : 0;
    __syncthreads();
    s[t] = v + add;
    __syncthreads();
  }
  if (t < NB) boff[t] = (t == 0) ? 0 : s[t - 1];
}

__global__ __launch_bounds__(SCAN_B) void scan_final_k(
    const int* __restrict__ cnt, const int* __restrict__ boff,
    int* __restrict__ off, int* __restrict__ cursor) {
  __shared__ int s[SCAN_B];
  const int t = threadIdx.x, b = blockIdx.x, i = b * SCAN_B + t;
  const int x = (i < N2) ? cnt[i] : 0;
  s[t] = x;
  __syncthreads();
  for (int st = 1; st < SCAN_B; st <<= 1) {
    const int v = s[t];
    const int add = (t >= st) ? s[t - st] : 0;
    __syncthreads();
    s[t] = v + add;
    __syncthreads();
  }
  if (i < N2) {
    const int o = boff[b] + s[t] - x;   // exclusive
    off[i] = o;
    cursor[i] = o;
  }
  if (i == N2 - 1) off[N2] = boff[b] + s[t];
}

// ---------------------------------------------------------------------------
// Kernel: CSR fill.  idx[0..NNZ) = member node per edge-slot;
//                    idx[NNZ..2*NNZ) = member edge per node-slot.
// (node cursors already carry the +NNZ base from the concatenated scan)
// ---------------------------------------------------------------------------
__global__ __launch_bounds__(256) void fill_k(
    const int* __restrict__ V, const int* __restrict__ E,
    int* __restrict__ cursor, int* __restrict__ idx) {
  const int i = blockIdx.x * blockDim.x + threadIdx.x;
  if (i < NNZ) {
    const int v = V[i], e = E[i];
    const int p = atomicAdd(&cursor[e], 1);
    idx[p] = v;
    const int q = atomicAdd(&cursor[NUM_EDGES + v], 1);
    idx[q] = e;
  }
}

// ---------------------------------------------------------------------------
// Kernel: per-edge gather.  16 threads per edge, each owning one float4
// column slot. Fuses De_sum, De_inv and the 1/cnt mean scale.
// ---------------------------------------------------------------------------
__global__ __launch_bounds__(256) void edge_gather_k(
    const int* __restrict__ off, const int* __restrict__ idx,
    const int* __restrict__ cnt, const float* __restrict__ Xp,
    float* __restrict__ Y) {
  const int g = blockIdx.x * blockDim.x + threadIdx.x;
  const int e = g >> 4, q = g & 15;
  if (e >= NUM_EDGES) return;
  const int beg = off[e], end = off[e + 1];
  const float4* Xp4 = (const float4*)Xp;
  float4 acc = make_float4(0.f, 0.f, 0.f, 0.f);
  float dsum = 0.f;
  for (int m = beg; m < end; ++m) {
    const int v = idx[m];
    const float4 x = Xp4[v * 16 + q];
    acc.x += x.x; acc.y += x.y; acc.z += x.z; acc.w += x.w;
    dsum += (float)cnt[NUM_EDGES + v];    // wave-broadcast (same addr x16)
  }
  const float ce = (float)(end - beg);
  const float De = dsum / (ce + 1.f);
  const float inv = (De > 0.f) ? rsqrtf(fmaxf(De, 1e-30f)) : 1.f;
  const float s = inv / fmaxf(ce, 1.f);
  ((float4*)Y)[e * 16 + q] = make_float4(acc.x * s, acc.y * s, acc.z * s, acc.w * s);
}

// ---------------------------------------------------------------------------
// Kernel: per-node gather.  Out[v,:] = Dv_inv * sum_e Y[e,:]
// ---------------------------------------------------------------------------
__global__ __launch_bounds__(256) void node_gather_k(
    const int* __restrict__ off, const int* __restrict__ idx,
    const int* __restrict__ cnt, const float* __restrict__ Y,
    float* __restrict__ Out) {
  const int g = blockIdx.x * blockDim.x + threadIdx.x;
  const int v = g >> 4, q = g & 15;
  if (v >= NUM_NODES) return;
  const int beg = off[NUM_EDGES + v], end = off[NUM_EDGES + v + 1];
  const float4* Y4 = (const float4*)Y;
  float4 acc = make_float4(0.f, 0.f, 0.f, 0.f);
  for (int m = beg; m < end; ++m) {
    const int e = idx[m];
    const float4 y = Y4[e * 16 + q];
    acc.x += y.x; acc.y += y.y; acc.z += y.z; acc.w += y.w;
  }
  const float d = (float)cnt[NUM_EDGES + v];
  const float s = (d > 0.f) ? rsqrtf(d) : 0.f;
  ((float4*)Out)[v * 16 + q] = make_float4(acc.x * s, acc.y * s, acc.z * s, acc.w * s);
}

extern "C" void kernel_launch(void* const* d_in, const int* in_sizes, int n_in,
                              void* d_out, int out_size, void* d_ws, size_t ws_size,
                              hipStream_t stream) {
  const float* X = (const float*)d_in[0];
  const int*   V = (const int*)d_in[1];
  const int*   E = (const int*)d_in[2];
  const float* W = (const float*)d_in[4];
  const float* b = (const float*)d_in[5];
  float* Out = (float*)d_out;

  // workspace layout
  float* Xp     = (float*)d_ws;                       // 25.6 MB
  float* Y      = Xp + (size_t)NUM_NODES * D;         // 25.6 MB
  int*   cnt    = (int*)(Y + (size_t)NUM_EDGES * D);  // 800 KB
  int*   off    = cnt + N2;                           // 800 KB (+1)
  int*   cursor = off + N2 + 1;                       // 800 KB
  int*   bsum   = cursor + N2;                        // pad to 1024
  int*   boff   = bsum + 1024;
  int*   idx    = boff + 1024;                        // 2*NNZ ints = 12.8 MB

  hipMemsetAsync(cnt, 0, (size_t)N2 * sizeof(int), stream);

  // 1. projection
  gemm_xw<<<NUM_NODES / GEMM_ROWS, 256, 0, stream>>>(X, W, b, Xp);
  // 2. histogram (edge sizes + node degrees)
  hist_k<<<(NNZ + 255) / 256, 256, 0, stream>>>(V, E, cnt);
  // 3. exclusive scan -> offsets + cursors
  scan_reduce_k<<<NB, SCAN_B, 0, stream>>>(cnt, bsum);
  scan_mid_k<<<1, 1024, 0, stream>>>(bsum, boff);
  scan_final_k<<<NB, SCAN_B, 0, stream>>>(cnt, boff, off, cursor);
  // 4. CSR fill (both directions in one pass)
  fill_k<<<(NNZ + 255) / 256, 256, 0, stream>>>(V, E, cursor, idx);
  // 5. per-edge gather + fused normalization
  edge_gather_k<<<NUM_EDGES * 16 / 256, 256, 0, stream>>>(off, idx, cnt, Xp, Y);
  // 6. per-node gather + fused Dv_inv
  node_gather_k<<<NUM_NODES * 16 / 256, 256, 0, stream>>>(off, idx, cnt, Y, Out);
}